// Round 1
// baseline (950.021 us; speedup 1.0000x reference)
//
#include <hip/hip_runtime.h>
#include <cstdint>

// Problem constants (from reference): B=4, S=1024, D=768, H=12, dh=64
#define BB 4
#define SS 1024
#define DD 768
#define HH 12
#define DH 64

// ---------------- generic fp32 tiled GEMM body ----------------
// 64x64 tile, BK=16, 4x4 per thread, 256 threads (16x16).
// A: [M,K] row-major lda. B: NN -> [K,N] ldb ; NT -> [N,K] ldb.
// C[m][n] = alpha * sum_k A[m][k]*B(k,n) (+ bias[n])
constexpr int BM = 64, BN = 64, BK = 16, TM = 4, TN = 4;

template<bool TRANS_B, bool HAS_BIAS>
__device__ __forceinline__ void gemm_body(
    const float* __restrict__ A, const float* __restrict__ B,
    const float* __restrict__ bias, float* __restrict__ C,
    int K, int lda, int ldb, int ldc, float alpha, int m0, int n0)
{
    __shared__ float As[BK][BM + 4];  // stored transposed: As[kk][m]
    __shared__ float Bs[BK][BN];      // Bs[kk][n]

    const int tid = threadIdx.x;
    const int tx = tid & 15;      // n-dim
    const int ty = tid >> 4;      // m-dim

    // A (and NT-B) load pattern: one float4 per thread per tile
    const int a_m = tid >> 2;         // 0..63
    const int a_k = (tid & 3) * 4;    // 0,4,8,12
    // NN-B load pattern
    const int b_k = tid >> 4;         // 0..15
    const int b_n = (tid & 15) * 4;   // 0..60

    float acc[TM][TN] = {};

    for (int k0 = 0; k0 < K; k0 += BK) {
        // issue global loads early (prefetch before the barrier)
        const float4 av = *(const float4*)&A[(size_t)(m0 + a_m) * lda + (k0 + a_k)];
        float4 bv;
        if (TRANS_B) bv = *(const float4*)&B[(size_t)(n0 + a_m) * ldb + (k0 + a_k)];
        else         bv = *(const float4*)&B[(size_t)(k0 + b_k) * ldb + (n0 + b_n)];

        __syncthreads();   // previous tile's compute done before overwriting LDS
        As[a_k + 0][a_m] = av.x; As[a_k + 1][a_m] = av.y;
        As[a_k + 2][a_m] = av.z; As[a_k + 3][a_m] = av.w;
        if (TRANS_B) {
            Bs[a_k + 0][a_m] = bv.x; Bs[a_k + 1][a_m] = bv.y;
            Bs[a_k + 2][a_m] = bv.z; Bs[a_k + 3][a_m] = bv.w;
        } else {
            *(float4*)&Bs[b_k][b_n] = bv;
        }
        __syncthreads();

#pragma unroll
        for (int kk = 0; kk < BK; ++kk) {
            const float4 a4 = *(const float4*)&As[kk][ty * TM];
            const float4 b4 = *(const float4*)&Bs[kk][tx * TN];
            const float a[4] = {a4.x, a4.y, a4.z, a4.w};
            const float b[4] = {b4.x, b4.y, b4.z, b4.w};
#pragma unroll
            for (int i = 0; i < TM; ++i)
#pragma unroll
                for (int j = 0; j < TN; ++j)
                    acc[i][j] += a[i] * b[j];
        }
    }

    // epilogue: float4 stores
#pragma unroll
    for (int i = 0; i < TM; ++i) {
        const int m = m0 + ty * TM + i;
        const int n = n0 + tx * TN;
        float4 v;
        v.x = acc[i][0] * alpha; v.y = acc[i][1] * alpha;
        v.z = acc[i][2] * alpha; v.w = acc[i][3] * alpha;
        if (HAS_BIAS) {
            v.x += bias[n + 0]; v.y += bias[n + 1];
            v.z += bias[n + 2]; v.w += bias[n + 3];
        }
        *(float4*)&C[(size_t)m * ldc + n] = v;
    }
}

// ---------------- kernels ----------------

// C = A @ B + bias   (grid: x = N/64, y = M/64)
__global__ __launch_bounds__(256) void gemm_nn_bias_kernel(
    const float* __restrict__ A, const float* __restrict__ B,
    const float* __restrict__ bias, float* __restrict__ C,
    int K, int lda, int ldb, int ldc)
{
    gemm_body<false, true>(A, B, bias, C, K, lda, ldb, ldc, 1.0f,
                           blockIdx.y * BM, blockIdx.x * BN);
}

// attn[hb, qi, ki] = scale * q[b,h,qi,:] . k[b,h,ki,:]
// qkv layout: [B*S, 3*D] rows, column = c*768 + h*64 + d
__global__ __launch_bounds__(256) void qk_kernel(
    const float* __restrict__ qkv, float* __restrict__ attn, int b_off, float scale)
{
    const int hb = blockIdx.z;
    const int b = b_off + hb / HH;
    const int h = hb % HH;
    const float* q = qkv + (size_t)b * SS * (3 * DD) + h * DH;          // lda = 2304
    const float* km = q + DD;                                            // k slice
    float* c = attn + (size_t)hb * SS * SS;
    gemm_body<true, false>(q, km, nullptr, c, DH, 3 * DD, 3 * DD, SS, scale,
                           blockIdx.y * BM, blockIdx.x * BN);
}

// ctx[b, qi, h*64+d] = sum_k attn[hb,qi,k] * v[b,h,k,d]
__global__ __launch_bounds__(256) void pv_kernel(
    const float* __restrict__ qkv, const float* __restrict__ attn,
    float* __restrict__ ctx, int b_off)
{
    const int hb = blockIdx.z;
    const int b = b_off + hb / HH;
    const int h = hb % HH;
    const float* a = attn + (size_t)hb * SS * SS;                        // lda = 1024
    const float* v = qkv + (size_t)b * SS * (3 * DD) + 2 * DD + h * DH;  // ldb = 2304
    float* c = ctx + (size_t)b * SS * DD + h * DH;                       // ldc = 768
    gemm_body<false, false>(a, v, nullptr, c, SS, SS, 3 * DD, DD, 1.0f,
                            blockIdx.y * BM, blockIdx.x * BN);
}

// In-place per-(b,q)-row: mix1 (Wl,bl) -> softmax over k -> mix2 (Ww,bw)
// grid.x = b_per * S ; 256 threads ; attn indexed with LOCAL batch.
__global__ __launch_bounds__(256) void mix_softmax_kernel(
    float* __restrict__ attn,
    const float* __restrict__ Wl, const float* __restrict__ bl,
    const float* __restrict__ Ww, const float* __restrict__ bw)
{
    __shared__ float buf[HH][SS];          // 48 KB
    __shared__ float wlS[HH * HH], wwS[HH * HH], blS[HH], bwS[HH];
    __shared__ float red[4];
    __shared__ float invden[HH];

    const int tid = threadIdx.x;
    const int bL = blockIdx.x >> 10;       // local batch (S = 1024)
    const int qi = blockIdx.x & (SS - 1);
    float* base = attn + ((size_t)bL * HH * SS + qi) * SS;  // head h row: base + h*S*S

    if (tid < HH * HH) { wlS[tid] = Wl[tid]; wwS[tid] = Ww[tid]; }
    if (tid < HH)      { blS[tid] = bl[tid]; bwS[tid] = bw[tid]; }

    for (int h = 0; h < HH; ++h)
        for (int k = tid; k < SS; k += 256)
            buf[h][k] = base[(size_t)h * SS * SS + k];
    __syncthreads();

    // mix1: column-local (each thread owns columns tid+256j) -> no barrier needed
    for (int j = 0; j < 4; ++j) {
        const int kc = tid + j * 256;
        float vin[HH], vout[HH];
#pragma unroll
        for (int h = 0; h < HH; ++h) vin[h] = buf[h][kc];
#pragma unroll
        for (int g = 0; g < HH; ++g) {
            float s = blS[g];
#pragma unroll
            for (int h = 0; h < HH; ++h) s += vin[h] * wlS[h * HH + g];
            vout[g] = s;
        }
#pragma unroll
        for (int g = 0; g < HH; ++g) buf[g][kc] = vout[g];
    }
    __syncthreads();

    // softmax per head row (over 1024 k)
    for (int g = 0; g < HH; ++g) {
        float m = -1e30f;
        for (int j = 0; j < 4; ++j) m = fmaxf(m, buf[g][tid + j * 256]);
        for (int off = 32; off; off >>= 1) m = fmaxf(m, __shfl_xor(m, off));
        if ((tid & 63) == 0) red[tid >> 6] = m;
        __syncthreads();
        m = fmaxf(fmaxf(red[0], red[1]), fmaxf(red[2], red[3]));
        __syncthreads();

        float ps = 0.f;
        for (int j = 0; j < 4; ++j) {
            const int kc = tid + j * 256;
            const float e = __expf(buf[g][kc] - m);
            buf[g][kc] = e;
            ps += e;
        }
        for (int off = 32; off; off >>= 1) ps += __shfl_xor(ps, off);
        if ((tid & 63) == 0) red[tid >> 6] = ps;
        __syncthreads();
        ps = red[0] + red[1] + red[2] + red[3];
        if (tid == 0) invden[g] = 1.0f / ps;
        __syncthreads();
    }

    // mix2 with folded normalization: column-local again
    for (int j = 0; j < 4; ++j) {
        const int kc = tid + j * 256;
        float vin[HH], vout[HH];
#pragma unroll
        for (int h = 0; h < HH; ++h) vin[h] = buf[h][kc] * invden[h];
#pragma unroll
        for (int g = 0; g < HH; ++g) {
            float s = bwS[g];
#pragma unroll
            for (int h = 0; h < HH; ++h) s += vin[h] * wwS[h * HH + g];
            vout[g] = s;
        }
#pragma unroll
        for (int g = 0; g < HH; ++g) buf[g][kc] = vout[g];
    }
    __syncthreads();

    for (int h = 0; h < HH; ++h)
        for (int k = tid; k < SS; k += 256)
            base[(size_t)h * SS * SS + k] = buf[h][k];
}

// ---------------- launch ----------------
extern "C" void kernel_launch(void* const* d_in, const int* in_sizes, int n_in,
                              void* d_out, int out_size, void* d_ws, size_t ws_size,
                              hipStream_t stream)
{
    const float* x     = (const float*)d_in[0];
    const float* Wqkv  = (const float*)d_in[1];
    const float* bqkv  = (const float*)d_in[2];
    const float* Wl    = (const float*)d_in[3];
    const float* bl    = (const float*)d_in[4];
    const float* Ww    = (const float*)d_in[5];
    const float* bw    = (const float*)d_in[6];
    const float* Wproj = (const float*)d_in[7];
    const float* bproj = (const float*)d_in[8];
    float* out = (float*)d_out;

    // workspace layout: [qkv | ctx | attn]
    float* qkv = (float*)d_ws;                              // B*S*3D = 9,437,184 f
    float* ctx = qkv + (size_t)BB * SS * 3 * DD;            // B*S*D  = 3,145,728 f
    float* attn = ctx + (size_t)BB * SS * DD;

    const size_t need_full = ((size_t)BB * SS * 3 * DD + (size_t)BB * SS * DD +
                              (size_t)BB * HH * SS * SS) * sizeof(float);   // 240 MB
    const bool full = (ws_size >= need_full);
    const int b_per  = full ? BB : 1;
    const int n_iter = full ? 1 : BB;
    const float scale = 0.125f;   // dh^-0.5, dh = 64

    const dim3 blk(256);

    // 1) qkv = x @ Wqkv + bqkv    [4096 x 2304 x 768]
    gemm_nn_bias_kernel<<<dim3((3 * DD) / BN, (BB * SS) / BM), blk, 0, stream>>>(
        x, Wqkv, bqkv, qkv, DD, DD, 3 * DD, 3 * DD);

    for (int it = 0; it < n_iter; ++it) {
        const int b0 = it * b_per;
        // 2) attn = scale * Q K^T per (b,h)
        qk_kernel<<<dim3(SS / BN, SS / BM, b_per * HH), blk, 0, stream>>>(
            qkv, attn, b0, scale);
        // 3) mix1 + softmax + mix2 in place
        mix_softmax_kernel<<<dim3(b_per * SS), blk, 0, stream>>>(
            attn, Wl, bl, Ww, bw);
        // 4) ctx = attn2 @ V per (b,h)
        pv_kernel<<<dim3(DH / BN, SS / BM, b_per * HH), blk, 0, stream>>>(
            qkv, attn, ctx, b0);
    }

    // 5) out = ctx @ Wproj + bproj   [4096 x 768 x 768]
    gemm_nn_bias_kernel<<<dim3(DD / BN, (BB * SS) / BM), blk, 0, stream>>>(
        ctx, Wproj, bproj, out, DD, DD, DD, DD);
}

// Round 2
// 617.891 us; speedup vs baseline: 1.5375x; 1.5375x over previous
//
#include <hip/hip_runtime.h>
#include <cstdint>

// Problem constants (from reference): B=4, S=1024, D=768, H=12, dh=64
#define BB 4
#define SS 1024
#define DD 768
#define HH 12
#define DH 64

// ---------------- generic fp32 tiled GEMM body ----------------
// 64x64 tile, BK=16, 4x4 per thread, 256 threads (16x16).
constexpr int BM = 64, BN = 64, BK = 16, TM = 4, TN = 4;

template<bool TRANS_B, bool HAS_BIAS>
__device__ __forceinline__ void gemm_body(
    const float* __restrict__ A, const float* __restrict__ B,
    const float* __restrict__ bias, float* __restrict__ C,
    int K, int lda, int ldb, int ldc, float alpha, int m0, int n0)
{
    __shared__ float As[BK][BM + 4];  // stored transposed: As[kk][m]
    __shared__ float Bs[BK][BN];      // Bs[kk][n]

    const int tid = threadIdx.x;
    const int tx = tid & 15;      // n-dim
    const int ty = tid >> 4;      // m-dim

    const int a_m = tid >> 2;         // 0..63
    const int a_k = (tid & 3) * 4;    // 0,4,8,12
    const int b_k = tid >> 4;         // 0..15
    const int b_n = (tid & 15) * 4;   // 0..60

    float acc[TM][TN] = {};

    for (int k0 = 0; k0 < K; k0 += BK) {
        const float4 av = *(const float4*)&A[(size_t)(m0 + a_m) * lda + (k0 + a_k)];
        float4 bv;
        if (TRANS_B) bv = *(const float4*)&B[(size_t)(n0 + a_m) * ldb + (k0 + a_k)];
        else         bv = *(const float4*)&B[(size_t)(k0 + b_k) * ldb + (n0 + b_n)];

        __syncthreads();
        As[a_k + 0][a_m] = av.x; As[a_k + 1][a_m] = av.y;
        As[a_k + 2][a_m] = av.z; As[a_k + 3][a_m] = av.w;
        if (TRANS_B) {
            Bs[a_k + 0][a_m] = bv.x; Bs[a_k + 1][a_m] = bv.y;
            Bs[a_k + 2][a_m] = bv.z; Bs[a_k + 3][a_m] = bv.w;
        } else {
            *(float4*)&Bs[b_k][b_n] = bv;
        }
        __syncthreads();

#pragma unroll
        for (int kk = 0; kk < BK; ++kk) {
            const float4 a4 = *(const float4*)&As[kk][ty * TM];
            const float4 b4 = *(const float4*)&Bs[kk][tx * TN];
            const float a[4] = {a4.x, a4.y, a4.z, a4.w};
            const float b[4] = {b4.x, b4.y, b4.z, b4.w};
#pragma unroll
            for (int i = 0; i < TM; ++i)
#pragma unroll
                for (int j = 0; j < TN; ++j)
                    acc[i][j] += a[i] * b[j];
        }
    }

#pragma unroll
    for (int i = 0; i < TM; ++i) {
        const int m = m0 + ty * TM + i;
        const int n = n0 + tx * TN;
        float4 v;
        v.x = acc[i][0] * alpha; v.y = acc[i][1] * alpha;
        v.z = acc[i][2] * alpha; v.w = acc[i][3] * alpha;
        if (HAS_BIAS) {
            v.x += bias[n + 0]; v.y += bias[n + 1];
            v.z += bias[n + 2]; v.w += bias[n + 3];
        }
        *(float4*)&C[(size_t)m * ldc + n] = v;
    }
}

// ---------------- kernels ----------------

__global__ __launch_bounds__(256) void gemm_nn_bias_kernel(
    const float* __restrict__ A, const float* __restrict__ B,
    const float* __restrict__ bias, float* __restrict__ C,
    int K, int lda, int ldb, int ldc)
{
    gemm_body<false, true>(A, B, bias, C, K, lda, ldb, ldc, 1.0f,
                           blockIdx.y * BM, blockIdx.x * BN);
}

__global__ __launch_bounds__(256) void qk_kernel(
    const float* __restrict__ qkv, float* __restrict__ attn, int b_off, float scale)
{
    const int hb = blockIdx.z;
    const int b = b_off + hb / HH;
    const int h = hb % HH;
    const float* q = qkv + (size_t)b * SS * (3 * DD) + h * DH;          // lda = 2304
    const float* km = q + DD;                                            // k slice
    float* c = attn + (size_t)hb * SS * SS;
    gemm_body<true, false>(q, km, nullptr, c, DH, 3 * DD, 3 * DD, SS, scale,
                           blockIdx.y * BM, blockIdx.x * BN);
}

__global__ __launch_bounds__(256) void pv_kernel(
    const float* __restrict__ qkv, const float* __restrict__ attn,
    float* __restrict__ ctx, int b_off)
{
    const int hb = blockIdx.z;
    const int b = b_off + hb / HH;
    const int h = hb % HH;
    const float* a = attn + (size_t)hb * SS * SS;                        // lda = 1024
    const float* v = qkv + (size_t)b * SS * (3 * DD) + 2 * DD + h * DH;  // ldb = 2304
    float* c = ctx + (size_t)b * SS * DD + h * DH;                       // ldc = 768
    gemm_body<false, false>(a, v, nullptr, c, SS, SS, 3 * DD, DD, 1.0f,
                            blockIdx.y * BM, blockIdx.x * BN);
}

// In-place per-(b,q)-row: mix1 (Wl,bl) -> softmax over k -> mix2 (Ww,bw)
// Rewritten: float4 staging, wave-parallel barrier-free softmax (wave w owns
// heads {w, w+4, w+8}), vectorized column-local mixes. 3 block barriers total
// in the hot path (vs 48+ before).
__global__ __launch_bounds__(256) void mix_softmax_kernel(
    float* __restrict__ attn,
    const float* __restrict__ Wl, const float* __restrict__ bl,
    const float* __restrict__ Ww, const float* __restrict__ bw)
{
    __shared__ float buf[HH][SS];          // 48 KB
    __shared__ float wlS[HH * HH], wwS[HH * HH], blS[HH], bwS[HH];
    __shared__ float invden[HH];

    const int tid  = threadIdx.x;
    const int wave = tid >> 6;
    const int lane = tid & 63;
    const int bL = blockIdx.x >> 10;       // local batch (S = 1024)
    const int qi = blockIdx.x & (SS - 1);
    float* base = attn + ((size_t)bL * HH * SS + qi) * SS;  // head h row: + h*S*S

    if (tid < HH * HH) { wlS[tid] = Wl[tid]; wwS[tid] = Ww[tid]; }
    if (tid < HH)      { blS[tid] = bl[tid]; bwS[tid] = bw[tid]; }

    // stage in: one float4 per head per thread, fully coalesced
    const int kc = tid * 4;
#pragma unroll
    for (int h = 0; h < HH; ++h)
        *(float4*)&buf[h][kc] = *(const float4*)&base[(size_t)h * SS * SS + kc];
    __syncthreads();

    // ---- mix1: column-local over this thread's 4 columns, no barrier needed
    {
        float4 vin[HH];
#pragma unroll
        for (int h = 0; h < HH; ++h) vin[h] = *(const float4*)&buf[h][kc];
#pragma unroll
        for (int g = 0; g < HH; ++g) {
            float4 s = {blS[g], blS[g], blS[g], blS[g]};
#pragma unroll
            for (int h = 0; h < HH; ++h) {
                const float w = wlS[h * HH + g];
                s.x += vin[h].x * w; s.y += vin[h].y * w;
                s.z += vin[h].z * w; s.w += vin[h].w * w;
            }
            *(float4*)&buf[g][kc] = s;
        }
    }
    __syncthreads();

    // ---- softmax: wave w handles heads w, w+4, w+8; butterfly reductions only
#pragma unroll
    for (int rep = 0; rep < 3; ++rep) {
        const int g = rep * 4 + wave;
        float4 v[4];
#pragma unroll
        for (int j = 0; j < 4; ++j)
            v[j] = *(const float4*)&buf[g][lane * 4 + j * 256];

        float m = -1e30f;
#pragma unroll
        for (int j = 0; j < 4; ++j)
            m = fmaxf(m, fmaxf(fmaxf(v[j].x, v[j].y), fmaxf(v[j].z, v[j].w)));
#pragma unroll
        for (int off = 32; off; off >>= 1) m = fmaxf(m, __shfl_xor(m, off));

        float ps = 0.f;
#pragma unroll
        for (int j = 0; j < 4; ++j) {
            v[j].x = __expf(v[j].x - m); v[j].y = __expf(v[j].y - m);
            v[j].z = __expf(v[j].z - m); v[j].w = __expf(v[j].w - m);
            ps += (v[j].x + v[j].y) + (v[j].z + v[j].w);
        }
#pragma unroll
        for (int off = 32; off; off >>= 1) ps += __shfl_xor(ps, off);

#pragma unroll
        for (int j = 0; j < 4; ++j)
            *(float4*)&buf[g][lane * 4 + j * 256] = v[j];
        if (lane == 0) invden[g] = 1.0f / ps;
    }
    __syncthreads();

    // ---- mix2 with folded normalization: column-local again
    {
        float4 vin[HH];
#pragma unroll
        for (int h = 0; h < HH; ++h) {
            float4 t = *(const float4*)&buf[h][kc];
            const float inv = invden[h];
            t.x *= inv; t.y *= inv; t.z *= inv; t.w *= inv;
            vin[h] = t;
        }
#pragma unroll
        for (int g = 0; g < HH; ++g) {
            float4 s = {bwS[g], bwS[g], bwS[g], bwS[g]};
#pragma unroll
            for (int h = 0; h < HH; ++h) {
                const float w = wwS[h * HH + g];
                s.x += vin[h].x * w; s.y += vin[h].y * w;
                s.z += vin[h].z * w; s.w += vin[h].w * w;
            }
            *(float4*)&buf[g][kc] = s;
        }
    }
    __syncthreads();

    // stage out
#pragma unroll
    for (int h = 0; h < HH; ++h)
        *(float4*)&base[(size_t)h * SS * SS + kc] = *(const float4*)&buf[h][kc];
}

// ---------------- launch ----------------
extern "C" void kernel_launch(void* const* d_in, const int* in_sizes, int n_in,
                              void* d_out, int out_size, void* d_ws, size_t ws_size,
                              hipStream_t stream)
{
    const float* x     = (const float*)d_in[0];
    const float* Wqkv  = (const float*)d_in[1];
    const float* bqkv  = (const float*)d_in[2];
    const float* Wl    = (const float*)d_in[3];
    const float* bl    = (const float*)d_in[4];
    const float* Ww    = (const float*)d_in[5];
    const float* bw    = (const float*)d_in[6];
    const float* Wproj = (const float*)d_in[7];
    const float* bproj = (const float*)d_in[8];
    float* out = (float*)d_out;

    // workspace layout: [qkv | ctx | attn]
    float* qkv = (float*)d_ws;                              // B*S*3D floats
    float* ctx = qkv + (size_t)BB * SS * 3 * DD;            // B*S*D floats
    float* attn = ctx + (size_t)BB * SS * DD;

    const size_t need_full = ((size_t)BB * SS * 3 * DD + (size_t)BB * SS * DD +
                              (size_t)BB * HH * SS * SS) * sizeof(float);   // 240 MB
    const bool full = (ws_size >= need_full);
    const int b_per  = full ? BB : 1;
    const int n_iter = full ? 1 : BB;
    const float scale = 0.125f;   // dh^-0.5, dh = 64

    const dim3 blk(256);

    // 1) qkv = x @ Wqkv + bqkv    [4096 x 2304 x 768]
    gemm_nn_bias_kernel<<<dim3((3 * DD) / BN, (BB * SS) / BM), blk, 0, stream>>>(
        x, Wqkv, bqkv, qkv, DD, DD, 3 * DD, 3 * DD);

    for (int it = 0; it < n_iter; ++it) {
        const int b0 = it * b_per;
        // 2) attn = scale * Q K^T per (b,h)
        qk_kernel<<<dim3(SS / BN, SS / BM, b_per * HH), blk, 0, stream>>>(
            qkv, attn, b0, scale);
        // 3) mix1 + softmax + mix2 in place
        mix_softmax_kernel<<<dim3(b_per * SS), blk, 0, stream>>>(
            attn, Wl, bl, Ww, bw);
        // 4) ctx = attn2 @ V per (b,h)
        pv_kernel<<<dim3(DH / BN, SS / BM, b_per * HH), blk, 0, stream>>>(
            qkv, attn, ctx, b0);
    }

    // 5) out = ctx @ Wproj + bproj   [4096 x 768 x 768]
    gemm_nn_bias_kernel<<<dim3(DD / BN, (BB * SS) / BM), blk, 0, stream>>>(
        ctx, Wproj, bproj, out, DD, DD, DD, DD);
}

// Round 3
// 250.153 us; speedup vs baseline: 3.7978x; 2.4701x over previous
//
#include <hip/hip_runtime.h>
#include <cstdint>

// Problem constants: B=4, S=1024, D=768, H=12, dh=64
#define BB 4
#define SS 1024
#define DD 768
#define HH 12
#define DH 64

typedef unsigned short u16;
typedef unsigned int   u32;
typedef __attribute__((ext_vector_type(8))) short bf16x8;
typedef __attribute__((ext_vector_type(4))) float f32x4;

// fp32 -> bf16 RNE (finite values)
__device__ __forceinline__ u16 f2bf(float f) {
    u32 u = __float_as_uint(f);
    u += 0x7fffu + ((u >> 16) & 1u);
    return (u16)(u >> 16);
}
__device__ __forceinline__ float b2f(u32 lo16) {
    return __uint_as_float(lo16 << 16);
}
__device__ __forceinline__ u32 pack2(float a, float b) {
    return (u32)f2bf(a) | ((u32)f2bf(b) << 16);
}

// async global->LDS, 16 B per lane, LDS dest must be wave-uniform base (+lane*16)
#define ASYNC16(gp, lp) __builtin_amdgcn_global_load_lds( \
    (const __attribute__((address_space(1))) void*)(gp),  \
    (__attribute__((address_space(3))) void*)(lp), 16, 0, 0)

// ---------------- MFMA GEMM body (NT: A[M,K], B[N,K], both K-contiguous bf16) ----
// Tile BM_ x BN_, BK=32, 256 threads = 4 waves in 2x2; wave region (BM_/2)x(BN_/2).
// mfma_f32_16x16x32_bf16; frag layouts per learn_hip m89/m91:
//   A: lane holds A[m=lane&15][k=(lane>>4)*8 + j]   (ds_read_b128 from [m][32] rows)
//   B: lane holds B[k=(lane>>4)*8 + j][n=lane&15] == Bt[n=lane&15][k]  (NT rows)
//   C/D: col = lane&15, row = (lane>>4)*4 + reg
template<int BM_, int BN_, class Epi>
__device__ __forceinline__ void mfma_gemm(
    const u16* __restrict__ A, const u16* __restrict__ B,
    int K, int lda, int ldb, int m0, int n0, const Epi& epi)
{
    constexpr int MI = BM_ / 32;   // 16x16 frags per wave along m
    constexpr int NJ = BN_ / 32;
    __shared__ u16 Alds[BM_ * 32];
    __shared__ u16 Blds[BN_ * 32];

    const int tid  = threadIdx.x;
    const int wave = tid >> 6;
    const int lane = tid & 63;
    const int wr = wave >> 1, wc = wave & 1;

    const int ar = lane >> 2;          // staging: row within 16-row group
    const int ac = (lane & 3) * 8;     // staging: col (8 bf16 = 16 B)

    f32x4 acc[MI][NJ] = {};

    for (int k0 = 0; k0 < K; k0 += 32) {
        __syncthreads();               // previous compute done before overwrite
#pragma unroll
        for (int j = 0; j < BM_ / 64; ++j) {
            const int rb = wave * (BM_ / 4) + j * 16;
            ASYNC16(A + (size_t)(m0 + rb + ar) * lda + k0 + ac, &Alds[rb * 32]);
        }
#pragma unroll
        for (int j = 0; j < BN_ / 64; ++j) {
            const int rb = wave * (BN_ / 4) + j * 16;
            ASYNC16(B + (size_t)(n0 + rb + ar) * ldb + k0 + ac, &Blds[rb * 32]);
        }
        __syncthreads();               // drains vmcnt (global_load_lds) + lgkm

        bf16x8 af[MI], bfr[NJ];
#pragma unroll
        for (int mi = 0; mi < MI; ++mi)
            af[mi] = *(const bf16x8*)&Alds[(wr * (BM_ / 2) + mi * 16 + (lane & 15)) * 32 + (lane >> 4) * 8];
#pragma unroll
        for (int nj = 0; nj < NJ; ++nj)
            bfr[nj] = *(const bf16x8*)&Blds[(wc * (BN_ / 2) + nj * 16 + (lane & 15)) * 32 + (lane >> 4) * 8];
#pragma unroll
        for (int mi = 0; mi < MI; ++mi)
#pragma unroll
            for (int nj = 0; nj < NJ; ++nj)
                acc[mi][nj] = __builtin_amdgcn_mfma_f32_16x16x32_bf16(
                    af[mi], bfr[nj], acc[mi][nj], 0, 0, 0);
    }

#pragma unroll
    for (int mi = 0; mi < MI; ++mi)
#pragma unroll
        for (int nj = 0; nj < NJ; ++nj)
#pragma unroll
            for (int r = 0; r < 4; ++r)
                epi(m0 + wr * (BM_ / 2) + mi * 16 + (lane >> 4) * 4 + r,
                    n0 + wc * (BN_ / 2) + nj * 16 + (lane & 15),
                    acc[mi][nj][r]);
}

// ---------------- GEMM kernels ----------------

// qkv = x @ Wqkv^T(t) + bqkv ; scatter into qb (scaled), kb, vt (transposed)
__global__ __launch_bounds__(256) void qkv_gemm_kernel(
    const u16* __restrict__ xb, const u16* __restrict__ Wt,
    const float* __restrict__ bias,
    u16* __restrict__ qb, u16* __restrict__ kb, u16* __restrict__ vt)
{
    struct Epi {
        const float* bias; u16 *qb, *kb, *vt;
        __device__ void operator()(int m, int n, float v) const {
            const float val = v + bias[n];
            const int c = n / DD;                 // block-uniform (768 = 6*128)
            const int w = n - c * DD, h = w >> 6, d = w & 63;
            const int b = m >> 10, s = m & 1023;
            if (c == 0)
                qb[(((size_t)(b * HH + h) << 10) + s) * DH + d] = f2bf(val * 0.125f);
            else if (c == 1)
                kb[(((size_t)(b * HH + h) << 10) + s) * DH + d] = f2bf(val);
            else
                vt[((size_t)(b * HH + h) * DH + d) * SS + s] = f2bf(val);
        }
    } epi{bias, qb, kb, vt};
    mfma_gemm<128, 128>(xb, Wt, DD, DD, DD, blockIdx.y * 128, blockIdx.x * 128, epi);
}

// attn[bhL, q, k] = q . k  (per head-slice; A=qb slice, B=kb slice, K=64)
__global__ __launch_bounds__(256) void qk_gemm_kernel(
    const u16* __restrict__ qb, const u16* __restrict__ kb,
    u16* __restrict__ attn, int bh0)
{
    const int bhL = blockIdx.z;
    const int bh = bh0 + bhL;
    const u16* A = qb + (size_t)bh * SS * DH;
    const u16* B = kb + (size_t)bh * SS * DH;
    u16* C = attn + (size_t)bhL * SS * SS;
    struct Epi {
        u16* C;
        __device__ void operator()(int m, int n, float v) const {
            C[(size_t)m * SS + n] = f2bf(v);
        }
    } epi{C};
    mfma_gemm<128, 128>(A, B, DH, DH, DH, blockIdx.y * 128, blockIdx.x * 128, epi);
}

// ctx[b, q, h*64+d] = attn2[bhL,q,:] . vt[bh,d,:]   (K=1024, N=64)
__global__ __launch_bounds__(256) void pv_gemm_kernel(
    const u16* __restrict__ attn2, const u16* __restrict__ vt,
    u16* __restrict__ ctx, int bh0)
{
    const int bhL = blockIdx.z;
    const int bh = bh0 + bhL;
    const int b = bh / HH, h = bh % HH;
    const u16* A = attn2 + (size_t)bhL * SS * SS;
    const u16* B = vt + (size_t)bh * DH * SS;
    u16* C = ctx + (size_t)b * SS * DD + h * DH;
    struct Epi {
        u16* C;
        __device__ void operator()(int m, int n, float v) const {
            C[(size_t)m * DD + n] = f2bf(v);
        }
    } epi{C};
    mfma_gemm<128, 64>(A, B, SS, SS, SS, blockIdx.y * 128, 0, epi);
}

// out = ctx @ Wproj^T(t) + bproj   (fp32 output)
__global__ __launch_bounds__(256) void proj_gemm_kernel(
    const u16* __restrict__ ctx, const u16* __restrict__ Wt,
    const float* __restrict__ bias, float* __restrict__ out)
{
    struct Epi {
        float* out; const float* bias;
        __device__ void operator()(int m, int n, float v) const {
            out[(size_t)m * DD + n] = v + bias[n];
        }
    } epi{out, bias};
    mfma_gemm<128, 64>(ctx, Wt, DD, DD, DD, blockIdx.y * 128, blockIdx.x * 64, epi);
}

// ---------------- mix + softmax (bf16 in, bf16 out) ----------------
__global__ __launch_bounds__(256) void mix_softmax_kernel(
    const u16* __restrict__ attn, u16* __restrict__ attn2,
    const float* __restrict__ Wl, const float* __restrict__ bl,
    const float* __restrict__ Ww, const float* __restrict__ bw)
{
    __shared__ float buf[HH][SS];          // 48 KB
    __shared__ float wlS[HH * HH], wwS[HH * HH], blS[HH], bwS[HH];
    __shared__ float invden[HH];

    const int tid  = threadIdx.x;
    const int wave = tid >> 6;
    const int lane = tid & 63;
    const int bL = blockIdx.x >> 10;       // local batch within chunk
    const int qi = blockIdx.x & (SS - 1);
    const size_t base = ((size_t)bL * HH * SS + qi) * SS;   // + h*S*S per head

    if (tid < HH * HH) { wlS[tid] = Wl[tid]; wwS[tid] = Ww[tid]; }
    if (tid < HH)      { blS[tid] = bl[tid]; bwS[tid] = bw[tid]; }

    const int kc = tid * 4;
#pragma unroll
    for (int h = 0; h < HH; ++h) {
        const uint2 u = *(const uint2*)&attn[base + (size_t)h * SS * SS + kc];
        buf[h][kc + 0] = b2f(u.x & 0xffff); buf[h][kc + 1] = b2f(u.x >> 16);
        buf[h][kc + 2] = b2f(u.y & 0xffff); buf[h][kc + 3] = b2f(u.y >> 16);
    }
    __syncthreads();

    // mix1: column-local, no barrier
    {
        float4 vin[HH];
#pragma unroll
        for (int h = 0; h < HH; ++h) vin[h] = *(const float4*)&buf[h][kc];
#pragma unroll
        for (int g = 0; g < HH; ++g) {
            float4 s = {blS[g], blS[g], blS[g], blS[g]};
#pragma unroll
            for (int h = 0; h < HH; ++h) {
                const float w = wlS[h * HH + g];
                s.x += vin[h].x * w; s.y += vin[h].y * w;
                s.z += vin[h].z * w; s.w += vin[h].w * w;
            }
            *(float4*)&buf[g][kc] = s;
        }
    }
    __syncthreads();

    // softmax: wave w handles heads w, w+4, w+8 (barrier-free butterflies)
#pragma unroll
    for (int rep = 0; rep < 3; ++rep) {
        const int g = rep * 4 + wave;
        float4 v[4];
#pragma unroll
        for (int j = 0; j < 4; ++j)
            v[j] = *(const float4*)&buf[g][lane * 4 + j * 256];

        float m = -1e30f;
#pragma unroll
        for (int j = 0; j < 4; ++j)
            m = fmaxf(m, fmaxf(fmaxf(v[j].x, v[j].y), fmaxf(v[j].z, v[j].w)));
#pragma unroll
        for (int off = 32; off; off >>= 1) m = fmaxf(m, __shfl_xor(m, off));

        float ps = 0.f;
#pragma unroll
        for (int j = 0; j < 4; ++j) {
            v[j].x = __expf(v[j].x - m); v[j].y = __expf(v[j].y - m);
            v[j].z = __expf(v[j].z - m); v[j].w = __expf(v[j].w - m);
            ps += (v[j].x + v[j].y) + (v[j].z + v[j].w);
        }
#pragma unroll
        for (int off = 32; off; off >>= 1) ps += __shfl_xor(ps, off);

#pragma unroll
        for (int j = 0; j < 4; ++j)
            *(float4*)&buf[g][lane * 4 + j * 256] = v[j];
        if (lane == 0) invden[g] = 1.0f / ps;
    }
    __syncthreads();

    // mix2 with folded normalization; write bf16
    {
        float4 vin[HH];
#pragma unroll
        for (int h = 0; h < HH; ++h) {
            float4 t = *(const float4*)&buf[h][kc];
            const float inv = invden[h];
            t.x *= inv; t.y *= inv; t.z *= inv; t.w *= inv;
            vin[h] = t;
        }
#pragma unroll
        for (int g = 0; g < HH; ++g) {
            float4 s = {bwS[g], bwS[g], bwS[g], bwS[g]};
#pragma unroll
            for (int h = 0; h < HH; ++h) {
                const float w = wwS[h * HH + g];
                s.x += vin[h].x * w; s.y += vin[h].y * w;
                s.z += vin[h].z * w; s.w += vin[h].w * w;
            }
            uint2 p;
            p.x = pack2(s.x, s.y); p.y = pack2(s.z, s.w);
            *(uint2*)&attn2[base + (size_t)g * SS * SS + kc] = p;
        }
    }
}

// ---------------- conversion kernels ----------------

// fp32 -> bf16 elementwise (n multiple of 8)
__global__ __launch_bounds__(256) void cvt_bf16_kernel(
    const float* __restrict__ in, u16* __restrict__ out, int n8)
{
    const int i = blockIdx.x * 256 + threadIdx.x;
    if (i >= n8) return;
    const float4 a = ((const float4*)in)[i * 2];
    const float4 b = ((const float4*)in)[i * 2 + 1];
    uint4 p;
    p.x = pack2(a.x, a.y); p.y = pack2(a.z, a.w);
    p.z = pack2(b.x, b.y); p.w = pack2(b.z, b.w);
    ((uint4*)out)[i] = p;
}

// fp32 [R][C] -> bf16 [C][R] (transpose + convert), 32x32 tiles
__global__ __launch_bounds__(256) void cvt_transpose_kernel(
    const float* __restrict__ in, u16* __restrict__ out, int R, int C)
{
    __shared__ float t[32][33];
    const int c0 = blockIdx.x * 32, r0 = blockIdx.y * 32;
    const int tr = threadIdx.x >> 3;
    const int tc = (threadIdx.x & 7) * 4;
    const float4 v = *(const float4*)&in[(size_t)(r0 + tr) * C + c0 + tc];
    t[tc + 0][tr] = v.x; t[tc + 1][tr] = v.y;
    t[tc + 2][tr] = v.z; t[tc + 3][tr] = v.w;
    __syncthreads();
    uint2 p;
    p.x = pack2(t[tr][tc + 0], t[tr][tc + 1]);
    p.y = pack2(t[tr][tc + 2], t[tr][tc + 3]);
    *(uint2*)&out[(size_t)(c0 + tr) * R + r0 + tc] = p;
}

// ---------------- launch ----------------
extern "C" void kernel_launch(void* const* d_in, const int* in_sizes, int n_in,
                              void* d_out, int out_size, void* d_ws, size_t ws_size,
                              hipStream_t stream)
{
    const float* x     = (const float*)d_in[0];
    const float* Wqkv  = (const float*)d_in[1];
    const float* bqkv  = (const float*)d_in[2];
    const float* Wl    = (const float*)d_in[3];
    const float* bl    = (const float*)d_in[4];
    const float* Ww    = (const float*)d_in[5];
    const float* bw    = (const float*)d_in[6];
    const float* Wproj = (const float*)d_in[7];
    const float* bproj = (const float*)d_in[8];
    float* out = (float*)d_out;

    // workspace (bf16 elems)
    const size_t N_XB  = (size_t)BB * SS * DD;        // 3,145,728
    const size_t N_QB  = (size_t)BB * HH * SS * DH;   // 3,145,728
    const size_t N_WT  = (size_t)DD * 3 * DD;         // 1,769,472
    const size_t N_WP  = (size_t)DD * DD;             //   589,824
    const size_t N_AT1 = (size_t)HH * SS * SS;        // per-batch attn chunk elems

    u16* xb  = (u16*)d_ws;
    u16* qb  = xb  + N_XB;
    u16* kb  = qb  + N_QB;
    u16* vt  = kb  + N_QB;
    u16* ctx = vt  + N_QB;
    u16* Wqkv_t = ctx + N_XB;
    u16* Wproj_t = Wqkv_t + N_WT;
    u16* attn = Wproj_t + N_WP;   // b_per * N_AT1 elems
    // attn2 placed after attn (depends on b_per)

    const size_t fixed_bytes = (size_t)(N_XB * 2 + N_QB * 3 + N_WT + N_WP) * 2;
    int b_per = BB;
    while (b_per > 1 &&
           fixed_bytes + (size_t)b_per * N_AT1 * 2 * 2 > ws_size)
        b_per >>= 1;
    const int n_iter = BB / b_per;
    u16* attn2 = attn + (size_t)b_per * N_AT1;

    const dim3 blk(256);

    // 0) conversions
    cvt_bf16_kernel<<<dim3((N_XB / 8 + 255) / 256), blk, 0, stream>>>(x, xb, (int)(N_XB / 8));
    cvt_transpose_kernel<<<dim3(3 * DD / 32, DD / 32), blk, 0, stream>>>(Wqkv, Wqkv_t, DD, 3 * DD);
    cvt_transpose_kernel<<<dim3(DD / 32, DD / 32), blk, 0, stream>>>(Wproj, Wproj_t, DD, DD);

    // 1) QKV projection (writes qb scaled, kb, vt transposed)
    qkv_gemm_kernel<<<dim3(3 * DD / 128, BB * SS / 128), blk, 0, stream>>>(
        xb, Wqkv_t, bqkv, qb, kb, vt);

    for (int it = 0; it < n_iter; ++it) {
        const int bh0 = it * b_per * HH;
        // 2) logits
        qk_gemm_kernel<<<dim3(SS / 128, SS / 128, b_per * HH), blk, 0, stream>>>(
            qb, kb, attn, bh0);
        // 3) mix1 + softmax + mix2
        mix_softmax_kernel<<<dim3(b_per * SS), blk, 0, stream>>>(
            attn, attn2, Wl, bl, Ww, bw);
        // 4) PV
        pv_gemm_kernel<<<dim3(1, SS / 128, b_per * HH), blk, 0, stream>>>(
            attn2, vt, ctx, bh0);
    }

    // 5) output projection (fp32 out + bias)
    proj_gemm_kernel<<<dim3(DD / 64, BB * SS / 128), blk, 0, stream>>>(
        ctx, Wproj_t, bproj, out);
}